// Round 7
// baseline (1994.039 us; speedup 1.0000x reference)
//
#include <hip/hip_runtime.h>
#include <hip/hip_bf16.h>

#define NUM_STEPS 10
#define DT 0.1f

typedef __bf16 bf16_t;
typedef __bf16 bf16x8 __attribute__((ext_vector_type(8)));
typedef __bf16 bf16x4 __attribute__((ext_vector_type(4)));
typedef float f32x4 __attribute__((ext_vector_type(4)));

// async global->LDS, 16B per lane; LDS dst is wave-uniform base + lane*16
__device__ __forceinline__ void async16(const bf16_t* g, bf16_t* l) {
  __builtin_amdgcn_global_load_lds(
      (const __attribute__((address_space(1))) void*)g,
      (__attribute__((address_space(3))) void*)l, 16, 0, 0);
}

__global__ void cvt_f32_to_bf16(const float* __restrict__ in,
                                bf16_t* __restrict__ out, int n4) {
  int i = blockIdx.x * blockDim.x + threadIdx.x;
  if (i < n4) {
    float4 v = ((const float4*)in)[i];
    bf16x4 o = {(bf16_t)v.x, (bf16_t)v.y, (bf16_t)v.z, (bf16_t)v.w};
    ((bf16x4*)out)[i] = o;
  }
}

// one-shot: decay[h] = exp(-dt/tau[h])
__global__ void make_decay(const float* __restrict__ tau,
                           float* __restrict__ decay, int n) {
  int i = blockIdx.x * blockDim.x + threadIdx.x;
  if (i < n) decay[i] = __expf(-DT / tau[i]);
}

// C[M,N] = A[M,K] * B[N,K]^T   (NT, both row-major, K contiguous)
// Round 7: the ACTUAL m201 geometry. BM=BN=256, BK=64, 8 waves as 2M x 4N
// (per-wave 128x64), 4 phases per K-tile, each phase = {4-8 ds_read_b128 ->
// issue 2 gll for tile t+1 -> s_barrier -> lgkmcnt(0) -> setprio(1) 16 MFMA
// setprio(0) -> [vmcnt] -> s_barrier}. bF reused across phase pairs (24
// ds_reads per 64 MFMA = 0.375/MFMA). LDS: 2 x 64 KB double-buffer.
// Staging staggered in use-order (ks0 units first); counted vmcnt(4) TWICE
// per tile (mid + boundary), never 0 until the tail. Intensity: 131
// FLOP/staged-byte (vs 87 at 256x128). Grid = 8x16 = 128 blocks (half chip
// idle - deliberate: per-block throughput at the proven template is the
// decisive test; rounds 2-6 showed schedule changes at 256x128 are null).
// EPI=0: ihb(bf16) = acc + bias1[col] + bias2[col]
// EPI=1: pre = acc + ihb; hn = d*hb_prev + (1-d)*tanh(pre); hb_next = bf16(hn)
//        if writeOut: out_f32 = hn
template <int EPI>
__global__ __launch_bounds__(512, 2) void gemm_nt(
    const bf16_t* __restrict__ A, const bf16_t* __restrict__ Bw, int M, int N,
    int K, const float* __restrict__ bias1, const float* __restrict__ bias2,
    bf16_t* __restrict__ out_ihb, const bf16_t* __restrict__ ihb,
    const float* __restrict__ decay, const bf16_t* __restrict__ hb_prev,
    bf16_t* __restrict__ hb_next, float* __restrict__ out_f32, int writeOut) {
  extern __shared__ char smem[];  // 131072 B: 2 x 64 KB K-loop; 128 KB epi

  const int tid = threadIdx.x;
  const int lane = tid & 63;
  const int wave = tid >> 6;    // 0..7
  const int waveM = wave >> 2;  // 0..1  (128-row half of 256)
  const int waveN = wave & 3;   // 0..3  (64-col quarter of 256)

  // XCD swizzle: 128 blocks -> 16 per XCD as 2bx x ... = 4bx x 4by chunk
  const int lin = blockIdx.y * gridDim.x + blockIdx.x;  // 0..127
  const int xcd = lin & 7;
  const int slot_ = lin >> 3;                    // 0..15
  const int bx = (xcd & 1) * 4 + (slot_ & 3);    // 0..7  (N/256)
  const int by = (xcd >> 1) * 4 + (slot_ >> 2);  // 0..15 (M/256)
  const long bRow = (long)by * 256;
  const long bCol = (long)bx * 256;

  // staging: A/B each 16 row-groups of 16; wave w owns groups {w, w+8}.
  // lane -> row = lane&15, k = (lane>>4)*8 within a 32-wide k-slice.
  // LDS per buffer (elements): A group g at g*1024 + ks*512;
  //                            B group g at 16384 + g*1024 + ks*512.
  const int laneRow = lane & 15;
  const int laneK = (lane >> 4) << 3;
  const bf16_t* aGlo = A + (bRow + wave * 16 + laneRow) * (long)K + laneK;
  const bf16_t* aGhi = A + (bRow + (8 + wave) * 16 + laneRow) * (long)K + laneK;
  const bf16_t* bGlo = Bw + (bCol + wave * 16 + laneRow) * (long)K + laneK;
  const bf16_t* bGhi = Bw + (bCol + (8 + wave) * 16 + laneRow) * (long)K + laneK;

  f32x4 acc[8][4] = {};

  auto uA = [&](int buf, int k0, int ks) {  // 2 gll: A groups {w, w+8}
    bf16_t* base = (bf16_t*)(smem + buf * 65536);
    async16(aGlo + k0 + ks * 32, base + wave * 1024 + ks * 512);
    async16(aGhi + k0 + ks * 32, base + (8 + wave) * 1024 + ks * 512);
  };
  auto uB = [&](int buf, int k0, int ks) {  // 2 gll: B groups {w, w+8}
    bf16_t* base = (bf16_t*)(smem + buf * 65536);
    async16(bGlo + k0 + ks * 32, base + 16384 + wave * 1024 + ks * 512);
    async16(bGhi + k0 + ks * 32, base + 16384 + (8 + wave) * 1024 + ks * 512);
  };

  const int NT = K >> 6;  // 16 or 32 K-tiles; tile t in buf t&1

  // prologue: tile 0 in use-order (ks0 A, ks0 B, ks1 A, ks1 B) = 8 gll
  uA(0, 0, 0);
  uB(0, 0, 0);
  uA(0, 0, 1);
  uB(0, 0, 1);
  asm volatile("s_waitcnt vmcnt(4)" ::: "memory");  // ks0 units landed
  __builtin_amdgcn_s_barrier();
  __builtin_amdgcn_sched_barrier(0);

  for (int t = 0; t < NT; ++t) {
    const int cur = t & 1, nxt = cur ^ 1;
    const int k1 = (t + 1) << 6;
    const bool pf = (t + 1) < NT;
    const bf16_t* Ab = (const bf16_t*)(smem + cur * 65536);
    const bf16_t* Bb = Ab + 16384;
    bf16x8 aF[4], bF[4];

    // ---- ph0: rf 0-3, ks0 (8 ds_read; bF persists into ph1) ----
#pragma unroll
    for (int i = 0; i < 4; ++i)
      aF[i] = *(const bf16x8*)&Ab[(waveM * 8 + i) * 1024 + lane * 8];
#pragma unroll
    for (int u = 0; u < 4; ++u)
      bF[u] = *(const bf16x8*)&Bb[(waveN * 4 + u) * 1024 + lane * 8];
    if (pf) uA(nxt, k1, 0);
    __builtin_amdgcn_s_barrier();
    asm volatile("s_waitcnt lgkmcnt(0)" ::: "memory");
    __builtin_amdgcn_sched_barrier(0);
    __builtin_amdgcn_s_setprio(1);
#pragma unroll
    for (int i = 0; i < 4; ++i)
#pragma unroll
      for (int u = 0; u < 4; ++u)
        acc[i][u] = __builtin_amdgcn_mfma_f32_16x16x32_bf16(aF[i], bF[u],
                                                            acc[i][u], 0, 0, 0);
    __builtin_amdgcn_s_setprio(0);
    __builtin_amdgcn_sched_barrier(0);
    __builtin_amdgcn_s_barrier();

    // ---- ph1: rf 4-7, ks0 (4 ds_read; bF reused) ----
#pragma unroll
    for (int i = 0; i < 4; ++i)
      aF[i] = *(const bf16x8*)&Ab[(waveM * 8 + 4 + i) * 1024 + lane * 8];
    if (pf) uB(nxt, k1, 0);
    __builtin_amdgcn_s_barrier();
    asm volatile("s_waitcnt lgkmcnt(0)" ::: "memory");
    __builtin_amdgcn_sched_barrier(0);
    __builtin_amdgcn_s_setprio(1);
#pragma unroll
    for (int i = 0; i < 4; ++i)
#pragma unroll
      for (int u = 0; u < 4; ++u)
        acc[4 + i][u] = __builtin_amdgcn_mfma_f32_16x16x32_bf16(
            aF[i], bF[u], acc[4 + i][u], 0, 0, 0);
    __builtin_amdgcn_s_setprio(0);
    // mid-tile counted wait: this tile's ks1 units landed (leave t+1's 4)
    if (t < NT - 1) {
      asm volatile("s_waitcnt vmcnt(4)" ::: "memory");
    } else {
      asm volatile("s_waitcnt vmcnt(0)" ::: "memory");
    }
    __builtin_amdgcn_sched_barrier(0);
    __builtin_amdgcn_s_barrier();

    // ---- ph2: rf 0-3, ks1 (8 ds_read; bF persists into ph3) ----
#pragma unroll
    for (int i = 0; i < 4; ++i)
      aF[i] = *(const bf16x8*)&Ab[(waveM * 8 + i) * 1024 + 512 + lane * 8];
#pragma unroll
    for (int u = 0; u < 4; ++u)
      bF[u] = *(const bf16x8*)&Bb[(waveN * 4 + u) * 1024 + 512 + lane * 8];
    if (pf) uA(nxt, k1, 1);
    __builtin_amdgcn_s_barrier();
    asm volatile("s_waitcnt lgkmcnt(0)" ::: "memory");
    __builtin_amdgcn_sched_barrier(0);
    __builtin_amdgcn_s_setprio(1);
#pragma unroll
    for (int i = 0; i < 4; ++i)
#pragma unroll
      for (int u = 0; u < 4; ++u)
        acc[i][u] = __builtin_amdgcn_mfma_f32_16x16x32_bf16(aF[i], bF[u],
                                                            acc[i][u], 0, 0, 0);
    __builtin_amdgcn_s_setprio(0);
    __builtin_amdgcn_sched_barrier(0);
    __builtin_amdgcn_s_barrier();

    // ---- ph3: rf 4-7, ks1 (4 ds_read) ----
#pragma unroll
    for (int i = 0; i < 4; ++i)
      aF[i] = *(const bf16x8*)&Ab[(waveM * 8 + 4 + i) * 1024 + 512 + lane * 8];
    if (pf) uB(nxt, k1, 1);
    __builtin_amdgcn_s_barrier();
    asm volatile("s_waitcnt lgkmcnt(0)" ::: "memory");
    __builtin_amdgcn_sched_barrier(0);
    __builtin_amdgcn_s_setprio(1);
#pragma unroll
    for (int i = 0; i < 4; ++i)
#pragma unroll
      for (int u = 0; u < 4; ++u)
        acc[4 + i][u] = __builtin_amdgcn_mfma_f32_16x16x32_bf16(
            aF[i], bF[u], acc[4 + i][u], 0, 0, 0);
    __builtin_amdgcn_s_setprio(0);
    // boundary counted wait: tile t+1's ks0 units landed (leave its ks1)
    if (t < NT - 1) {
      asm volatile("s_waitcnt vmcnt(4)" ::: "memory");
    }
    __builtin_amdgcn_sched_barrier(0);
    __builtin_amdgcn_s_barrier();
  }
  // loop exits after a barrier; all LDS reads consumed -> Ep reuse safe

  // ---- epilogue: 2 passes of 128 rows through swizzled LDS ----
  // C/D layout: col = lane&15, row = (lane>>4)*4 + reg   [measured m89/m91]
  float* Ep = (float*)smem;  // 128 x 256 f32 = 128 KB
  const int eRow = (lane >> 4) << 2;
  const int eCol = lane & 15;
  const int rdRow = tid >> 2;  // 0..127
  const int rq = tid & 3;

  for (int p = 0; p < 2; ++p) {
    if (p) __syncthreads();  // pass-0 reads done before pass-1 overwrites Ep
    if (waveM == p) {
#pragma unroll
      for (int rf = 0; rf < 8; ++rf)
#pragma unroll
        for (int cf = 0; cf < 4; ++cf)
#pragma unroll
          for (int r = 0; r < 4; ++r) {
            const int rowL = rf * 16 + eRow + r;          // 0..127
            const int colL = waveN * 64 + cf * 16 + eCol;  // 0..255
            // swizzle: phys = row*256 + ((col + 4*row) & 255)  (2-way max)
            Ep[rowL * 256 + ((colL + 4 * rowL) & 255)] = acc[rf][cf][r];
          }
    }
    __syncthreads();

    const long grow = bRow + p * 128 + rdRow;
#pragma unroll
    for (int c4 = 0; c4 < 4; ++c4) {
      const int col0 = rq * 16 + c4 * 64;
      float v[16];
#pragma unroll
      for (int c = 0; c < 4; ++c)
        *(f32x4*)&v[c * 4] =
            *(const f32x4*)&Ep[rdRow * 256 + ((col0 + 4 * c + 4 * rdRow) & 255)];
      const long g = grow * (long)N + bCol + col0;

      if (EPI == 0) {
        f32x4 b1[4], b2[4];
#pragma unroll
        for (int c = 0; c < 4; ++c) {
          b1[c] = *(const f32x4*)&bias1[bCol + col0 + c * 4];
          b2[c] = *(const f32x4*)&bias2[bCol + col0 + c * 4];
        }
        bf16x8 o0, o1;
#pragma unroll
        for (int e = 0; e < 8; ++e)
          o0[e] = (bf16_t)(v[e] + b1[e >> 2][e & 3] + b2[e >> 2][e & 3]);
#pragma unroll
        for (int e = 0; e < 8; ++e)
          o1[e] = (bf16_t)(v[8 + e] + b1[2 + (e >> 2)][e & 3] +
                           b2[2 + (e >> 2)][e & 3]);
        *(bf16x8*)&out_ihb[g] = o0;  // 16B/lane
        *(bf16x8*)&out_ihb[g + 8] = o1;
      } else {
        const bf16x8 ih0 = *(const bf16x8*)&ihb[g];
        const bf16x8 ih1 = *(const bf16x8*)&ihb[g + 8];
        const bf16x8 hp0 = *(const bf16x8*)&hb_prev[g];
        const bf16x8 hp1 = *(const bf16x8*)&hb_prev[g + 8];
        f32x4 dc[4];
#pragma unroll
        for (int c = 0; c < 4; ++c)
          dc[c] = *(const f32x4*)&decay[bCol + col0 + c * 4];
        float hn[16];
        bf16x8 o0, o1;
#pragma unroll
        for (int e = 0; e < 8; ++e) {
          const float d = dc[e >> 2][e & 3];
          const float th = tanhf(v[e] + (float)ih0[e]);
          hn[e] = d * (float)hp0[e] + (1.0f - d) * th;
          o0[e] = (bf16_t)hn[e];
        }
#pragma unroll
        for (int e = 0; e < 8; ++e) {
          const float d = dc[2 + (e >> 2)][e & 3];
          const float th = tanhf(v[8 + e] + (float)ih1[e]);
          hn[8 + e] = d * (float)hp1[e] + (1.0f - d) * th;
          o1[e] = (bf16_t)hn[8 + e];
        }
        *(bf16x8*)&hb_next[g] = o0;
        *(bf16x8*)&hb_next[g + 8] = o1;
        if (writeOut) {
#pragma unroll
          for (int c = 0; c < 4; ++c)
            *(f32x4*)&out_f32[g + c * 4] = *(const f32x4*)&hn[c * 4];
        }
      }
    }
  }
}

extern "C" void kernel_launch(void* const* d_in, const int* in_sizes, int n_in,
                              void* d_out, int out_size, void* d_ws,
                              size_t ws_size, hipStream_t stream) {
  const float* x = (const float*)d_in[0];
  const float* h0 = (const float*)d_in[1];
  const float* W_ih = (const float*)d_in[2];
  const float* b_ih = (const float*)d_in[3];
  const float* W_hh = (const float*)d_in[4];
  const float* b_hh = (const float*)d_in[5];
  const float* tau = (const float*)d_in[6];
  float* hout = (float*)d_out;

  const int B = 4096, I = 1024, H = 2048;

  char* ws = (char*)d_ws;
  bf16_t* ihb = (bf16_t*)ws; ws += (size_t)B * H * 2;   // 16 MB
  bf16_t* hb0 = (bf16_t*)ws; ws += (size_t)B * H * 2;   // 16 MB
  bf16_t* hb1 = (bf16_t*)ws; ws += (size_t)B * H * 2;   // 16 MB
  bf16_t* xb = (bf16_t*)ws;  ws += (size_t)B * I * 2;   // 8 MB
  bf16_t* wihb = (bf16_t*)ws; ws += (size_t)H * I * 2;  // 4 MB
  bf16_t* whhb = (bf16_t*)ws; ws += (size_t)H * H * 2;  // 8 MB
  float* decay = (float*)ws; ws += (size_t)H * 4;       // 8 KB

  const int LDS_BYTES = 131072;  // 2 x 64 KB K-loop buffers; 128 KB epilogue
  (void)hipFuncSetAttribute(reinterpret_cast<const void*>(&gemm_nt<0>),
                            hipFuncAttributeMaxDynamicSharedMemorySize,
                            LDS_BYTES);
  (void)hipFuncSetAttribute(reinterpret_cast<const void*>(&gemm_nt<1>),
                            hipFuncAttributeMaxDynamicSharedMemorySize,
                            LDS_BYTES);

  cvt_f32_to_bf16<<<(B * I / 4 + 255) / 256, 256, 0, stream>>>(x, xb, B * I / 4);
  cvt_f32_to_bf16<<<(H * I / 4 + 255) / 256, 256, 0, stream>>>(W_ih, wihb, H * I / 4);
  cvt_f32_to_bf16<<<(H * H / 4 + 255) / 256, 256, 0, stream>>>(W_hh, whhb, H * H / 4);
  cvt_f32_to_bf16<<<(B * H / 4 + 255) / 256, 256, 0, stream>>>(h0, hb0, B * H / 4);
  make_decay<<<(H + 255) / 256, 256, 0, stream>>>(tau, decay, H);

  dim3 grid(H / 256, B / 256);  // (8, 16) = 128 blocks (256^2 tiles)
  // ihb = x @ W_ih^T + b_ih + b_hh   (fold both biases once, store bf16)
  gemm_nt<0><<<grid, 512, LDS_BYTES, stream>>>(
      xb, wihb, B, H, I, b_ih, b_hh, ihb, nullptr, nullptr, nullptr, nullptr,
      nullptr, 0);

  bf16_t* hb[2] = {hb0, hb1};
  for (int s = 0; s < NUM_STEPS; ++s) {
    gemm_nt<1><<<grid, 512, LDS_BYTES, stream>>>(
        hb[s & 1], whhb, B, H, H, nullptr, nullptr, nullptr, ihb, decay,
        hb[s & 1], hb[(s + 1) & 1], hout, (s == NUM_STEPS - 1) ? 1 : 0);
  }
}

// Round 8
// 698.880 us; speedup vs baseline: 2.8532x; 2.8532x over previous
//
#include <hip/hip_runtime.h>
#include <hip/hip_bf16.h>

#define NUM_STEPS 10
#define DT 0.1f

typedef __bf16 bf16_t;
typedef __bf16 bf16x8 __attribute__((ext_vector_type(8)));
typedef float f32x4 __attribute__((ext_vector_type(4)));

// one-shot: decay[h] = exp(-dt/tau[h])
__global__ void make_decay(const float* __restrict__ tau,
                           float* __restrict__ decay, int n) {
  int i = blockIdx.x * blockDim.x + threadIdx.x;
  if (i < n) decay[i] = __expf(-DT / tau[i]);
}

// f32 row-major [R][Kd] -> bf16 FRAG-LINEAR:
// elem (r,k) at ((r>>4)*(Kd/32) + (k>>5))*512 + ((r&15)+(((k>>3)&3)<<4))*8 + (k&7)
// (identical to the LDS image the gll staging built in rounds 1-6, so the
// MFMA operand a wave reads at base+lane*16B is byte-identical to before).
// ksh = log2(Kd/32). Writes are out[tid*8] -> perfectly coalesced.
__global__ void cvt_swz(const float* __restrict__ in, bf16_t* __restrict__ out,
                        int R, int Kd, int ksh) {
  const long tid = (long)blockIdx.x * blockDim.x + threadIdx.x;
  const long n = ((long)R * Kd) >> 3;
  if (tid >= n) return;
  const int slice = (int)(tid >> 6);
  const int lane = (int)tid & 63;
  const int g = slice >> ksh;
  const int s = slice & ((1 << ksh) - 1);
  const int r = (g << 4) + (lane & 15);
  const int k = (s << 5) + ((lane >> 4) << 3);
  const float4 v0 = *(const float4*)&in[(long)r * Kd + k];
  const float4 v1 = *(const float4*)&in[(long)r * Kd + k + 4];
  bf16x8 o = {(bf16_t)v0.x, (bf16_t)v0.y, (bf16_t)v0.z, (bf16_t)v0.w,
              (bf16_t)v1.x, (bf16_t)v1.y, (bf16_t)v1.z, (bf16_t)v1.w};
  *(bf16x8*)&out[tid << 3] = o;
}

// C[M,N] = A[M,K] * B[N,K]^T, A and B in FRAG-LINEAR layout (see cvt_swz).
// Round 8: ZERO-BARRIER, ZERO-LDS K-loop. Rounds 2-7 proved every
// barrier-coupled LDS-staging schedule pins at ~5.4k cyc/48KB tile
// (~10 B/cyc/CU); this removes the mechanism entirely. Each wave loads its
// MFMA fragments direct-to-register with coalesced dwordx4 (frag-linear
// layout makes frag load = base + lane*16B), software-pipelined one 32-wide
// k-slice ahead (two named register sets; compiler manages waits). LDS is
// used only by the verified swizzled epilogue. Geometry: BM=256 BN=128,
// 8 waves 4Mx2N (per-wave 64x64), grid 256 blocks, XCD swizzle kept.
// hb (the recurrent state) lives in frag-linear layout across steps: the
// EPI=1 epilogue reads hb_prev / writes hb_next at frag-linear addresses
// (two 16B chunks per 16-col group; each wave fills whole 128B lines).
// ihb and out_f32 stay row-major.
// EPI=0: ihb(bf16,row-major) = acc + bias1[col] + bias2[col]
// EPI=1: pre = acc + ihb; hn = d*hb_prev + (1-d)*tanh(pre); hb_next=bf16(hn)
//        if writeOut: out_f32 = hn
template <int EPI>
__global__ __launch_bounds__(512, 2) void gemm_nt(
    const bf16_t* __restrict__ A, const bf16_t* __restrict__ Bw, int M, int N,
    int K, const float* __restrict__ bias1, const float* __restrict__ bias2,
    bf16_t* __restrict__ out_ihb, const bf16_t* __restrict__ ihb,
    const float* __restrict__ decay, const bf16_t* __restrict__ hb_prev,
    bf16_t* __restrict__ hb_next, float* __restrict__ out_f32, int writeOut) {
  extern __shared__ char smem[];  // 128 KB, epilogue only

  const int tid = threadIdx.x;
  const int lane = tid & 63;
  const int wave = tid >> 6;    // 0..7
  const int waveM = wave >> 1;  // 0..3  (64-row band of 256)
  const int waveN = wave & 1;   // 0..1  (64-col half of 128)

  // XCD swizzle (verified mapping)
  const int lin = blockIdx.y * gridDim.x + blockIdx.x;  // 0..255
  const int xcd = lin & 7;
  const int slot_ = lin >> 3;                    // 0..31
  const int bx = (xcd & 1) * 8 + (slot_ & 7);    // 0..15 (N/128)
  const int by = (xcd >> 1) * 4 + (slot_ >> 3);  // 0..15 (M/256)
  const long bRow = (long)by * 256;
  const long bCol = (long)bx * 128;

  // frag-linear bases: row-group slab stride = 16*K elems
  const long KS = (long)K << 4;
  const bf16_t* aP = A + ((long)((bRow >> 4) + waveM * 4)) * KS + (lane << 3);
  const bf16_t* bP = Bw + ((long)((bCol >> 4) + waveN * 4)) * KS + (lane << 3);

  f32x4 acc[4][4] = {};

  auto LD = [&](bf16x8 aF[4], bf16x8 bF[4], int s) {
#pragma unroll
    for (int i = 0; i < 4; ++i)
      aF[i] = *(const bf16x8*)(aP + i * KS + ((long)s << 9));
#pragma unroll
    for (int u = 0; u < 4; ++u)
      bF[u] = *(const bf16x8*)(bP + u * KS + ((long)s << 9));
  };
  auto FM = [&](const bf16x8 aF[4], const bf16x8 bF[4]) {
#pragma unroll
    for (int i = 0; i < 4; ++i)
#pragma unroll
      for (int u = 0; u < 4; ++u)
        acc[i][u] = __builtin_amdgcn_mfma_f32_16x16x32_bf16(aF[i], bF[u],
                                                            acc[i][u], 0, 0, 0);
  };

  // ---- zero-barrier K-loop over NS = K/32 k-slices, 1-slice prefetch ----
  const int NS = K >> 5;  // 32 or 64, even
  bf16x8 a0[4], b0[4], a1[4], b1[4];
  LD(a0, b0, 0);
  int s = 0;
  for (; s + 2 < NS; s += 2) {
    LD(a1, b1, s + 1);
    FM(a0, b0);
    LD(a0, b0, s + 2);
    FM(a1, b1);
  }
  LD(a1, b1, s + 1);  // s == NS-2
  FM(a0, b0);
  FM(a1, b1);

  __syncthreads();  // epilogue LDS phase begins

  // ---- epilogue: LDS transpose (swizzled) then coalesced global I/O ----
  // C/D layout: col = lane&15, row = (lane>>4)*4 + reg   [measured m89/m91]
  float* Ep = (float*)smem;  // 256x128 f32 = 128 KB
  const int eRow = (lane >> 4) << 2;
  const int eCol = lane & 15;
#pragma unroll
  for (int i = 0; i < 4; ++i)
#pragma unroll
    for (int u = 0; u < 4; ++u)
#pragma unroll
      for (int r = 0; r < 4; ++r) {
        const int rowL = waveM * 64 + i * 16 + eRow + r;
        const int colL = waveN * 64 + u * 16 + eCol;
        // swizzle: phys = row*128 + ((col + 4*row) & 127)  (2-way max)
        Ep[rowL * 128 + ((colL + 4 * rowL) & 127)] = acc[i][u][r];
      }
  __syncthreads();

  // readers: row = p*64 + tid>>3, 16 consecutive cols at (tid&7)*16
  const int rdRow = tid >> 3;
  const int col0 = (tid & 7) * 16;
#pragma unroll
  for (int p = 0; p < 4; ++p) {
    const int row = p * 64 + rdRow;  // local row 0..255
    float v[16];
#pragma unroll
    for (int c = 0; c < 4; ++c)
      *(f32x4*)&v[c * 4] =
          *(const f32x4*)&Ep[row * 128 + ((col0 + 4 * c + 4 * row) & 127)];
    const long grow = bRow + row;
    const long g = grow * (long)N + bCol + col0;  // row-major addr

    if (EPI == 0) {
      f32x4 b1v[4], b2v[4];
#pragma unroll
      for (int c = 0; c < 4; ++c) {
        b1v[c] = *(const f32x4*)&bias1[bCol + col0 + c * 4];
        b2v[c] = *(const f32x4*)&bias2[bCol + col0 + c * 4];
      }
      bf16x8 o0, o1;
#pragma unroll
      for (int e = 0; e < 8; ++e)
        o0[e] = (bf16_t)(v[e] + b1v[e >> 2][e & 3] + b2v[e >> 2][e & 3]);
#pragma unroll
      for (int e = 0; e < 8; ++e)
        o1[e] = (bf16_t)(v[8 + e] + b1v[2 + (e >> 2)][e & 3] +
                         b2v[2 + (e >> 2)][e & 3]);
      *(bf16x8*)&out_ihb[g] = o0;  // row-major, 16B/lane
      *(bf16x8*)&out_ihb[g + 8] = o1;
    } else {
      // hb is FRAG-LINEAR (Kdim = N): chunk j covers cols col0+8j..+8j+7.
      // bRow%16==0 and bCol%128==0 -> local row/col0 give lane bits directly.
      const long fg = (grow >> 4) * ((long)N >> 5);
      const int s_ = (int)((bCol + col0) >> 5);
      const int l0 = (row & 15) + (((col0 >> 3) + 0) & 3) * 16;
      const int l1 = (row & 15) + (((col0 >> 3) + 1) & 3) * 16;
      const long fo = (fg + s_) << 9;
      const long o0a = fo + (l0 << 3);
      const long o1a = fo + (l1 << 3);
      const bf16x8 ih0 = *(const bf16x8*)&ihb[g];       // row-major
      const bf16x8 ih1 = *(const bf16x8*)&ihb[g + 8];
      const bf16x8 hp0 = *(const bf16x8*)&hb_prev[o0a]; // frag-linear
      const bf16x8 hp1 = *(const bf16x8*)&hb_prev[o1a];
      f32x4 dc[4];
#pragma unroll
      for (int c = 0; c < 4; ++c)
        dc[c] = *(const f32x4*)&decay[bCol + col0 + c * 4];
      float hn[16];
      bf16x8 o0, o1;
#pragma unroll
      for (int e = 0; e < 8; ++e) {
        const float d = dc[e >> 2][e & 3];
        const float th = tanhf(v[e] + (float)ih0[e]);
        hn[e] = d * (float)hp0[e] + (1.0f - d) * th;
        o0[e] = (bf16_t)hn[e];
      }
#pragma unroll
      for (int e = 0; e < 8; ++e) {
        const float d = dc[2 + (e >> 2)][e & 3];
        const float th = tanhf(v[8 + e] + (float)ih1[e]);
        hn[8 + e] = d * (float)hp1[e] + (1.0f - d) * th;
        o1[e] = (bf16_t)hn[8 + e];
      }
      *(bf16x8*)&hb_next[o0a] = o0;  // frag-linear
      *(bf16x8*)&hb_next[o1a] = o1;
      if (writeOut) {
#pragma unroll
        for (int c = 0; c < 4; ++c)
          *(f32x4*)&out_f32[g + c * 4] = *(const f32x4*)&hn[c * 4];
      }
    }
  }
}

extern "C" void kernel_launch(void* const* d_in, const int* in_sizes, int n_in,
                              void* d_out, int out_size, void* d_ws,
                              size_t ws_size, hipStream_t stream) {
  const float* x = (const float*)d_in[0];
  const float* h0 = (const float*)d_in[1];
  const float* W_ih = (const float*)d_in[2];
  const float* b_ih = (const float*)d_in[3];
  const float* W_hh = (const float*)d_in[4];
  const float* b_hh = (const float*)d_in[5];
  const float* tau = (const float*)d_in[6];
  float* hout = (float*)d_out;

  const int B = 4096, I = 1024, H = 2048;

  char* ws = (char*)d_ws;
  bf16_t* ihb = (bf16_t*)ws; ws += (size_t)B * H * 2;   // 16 MB (row-major)
  bf16_t* hb0 = (bf16_t*)ws; ws += (size_t)B * H * 2;   // 16 MB (frag-linear)
  bf16_t* hb1 = (bf16_t*)ws; ws += (size_t)B * H * 2;   // 16 MB (frag-linear)
  bf16_t* xb = (bf16_t*)ws;  ws += (size_t)B * I * 2;   // 8 MB (frag-linear)
  bf16_t* wihb = (bf16_t*)ws; ws += (size_t)H * I * 2;  // 4 MB (frag-linear)
  bf16_t* whhb = (bf16_t*)ws; ws += (size_t)H * H * 2;  // 8 MB (frag-linear)
  float* decay = (float*)ws; ws += (size_t)H * 4;       // 8 KB

  const int LDS_BYTES = 131072;  // epilogue 256x128 f32
  (void)hipFuncSetAttribute(reinterpret_cast<const void*>(&gemm_nt<0>),
                            hipFuncAttributeMaxDynamicSharedMemorySize,
                            LDS_BYTES);
  (void)hipFuncSetAttribute(reinterpret_cast<const void*>(&gemm_nt<1>),
                            hipFuncAttributeMaxDynamicSharedMemorySize,
                            LDS_BYTES);

  // one-shot conversions into frag-linear layout (ksh = log2(Kd/32))
  {
    long n;
    n = (long)B * I / 8;
    cvt_swz<<<(int)((n + 255) / 256), 256, 0, stream>>>(x, xb, B, I, 5);
    n = (long)H * I / 8;
    cvt_swz<<<(int)((n + 255) / 256), 256, 0, stream>>>(W_ih, wihb, H, I, 5);
    n = (long)H * H / 8;
    cvt_swz<<<(int)((n + 255) / 256), 256, 0, stream>>>(W_hh, whhb, H, H, 6);
    n = (long)B * H / 8;
    cvt_swz<<<(int)((n + 255) / 256), 256, 0, stream>>>(h0, hb0, B, H, 6);
  }
  make_decay<<<(H + 255) / 256, 256, 0, stream>>>(tau, decay, H);

  dim3 grid(H / 128, B / 256);  // (16, 16) = 256 blocks
  // ihb = x @ W_ih^T + b_ih + b_hh   (fold both biases once, store bf16)
  gemm_nt<0><<<grid, 512, LDS_BYTES, stream>>>(
      xb, wihb, B, H, I, b_ih, b_hh, ihb, nullptr, nullptr, nullptr, nullptr,
      nullptr, 0);

  bf16_t* hb[2] = {hb0, hb1};
  for (int s = 0; s < NUM_STEPS; ++s) {
    gemm_nt<1><<<grid, 512, LDS_BYTES, stream>>>(
        hb[s & 1], whhb, B, H, H, nullptr, nullptr, nullptr, ihb, decay,
        hb[s & 1], hb[(s + 1) & 1], hout, (s == NUM_STEPS - 1) ? 1 : 0);
  }
}